// Round 1
// baseline (914.365 us; speedup 1.0000x reference)
//
#include <hip/hip_runtime.h>
#include <math.h>

// ---------------------------------------------------------------------------
// GAT 2-layer forward. fp32 everywhere (threshold 3.1e-3 abs => stay exact).
// Pipeline:
//   CSR build (hist -> scan -> fill)           [graph is input, rebuilt per call]
//   feat1 = features @ W1                       (fp32 tiled GEMM, 128x128x16)
//   el1/er1 = einsum(feat1, al1/ar1)
//   h = ELU(aggregate_softmax(feat1, el1, er1)) (one wave per dst node)
//   feat2 = h @ W2                              (fp32 tiled GEMM, 128x64x16)
//   el2/er2 = einsum(feat2, al2/ar2)
//   out = head_mean(aggregate_softmax(feat2, el2, er2))
// ---------------------------------------------------------------------------

__global__ void hist_kernel(const int* __restrict__ dst, int* __restrict__ cnt, int E) {
    int e = blockIdx.x * blockDim.x + threadIdx.x;
    if (e < E) atomicAdd(&cnt[dst[e]], 1);
}

__global__ __launch_bounds__(1024) void scan_kernel(const int* __restrict__ cnt,
                                                    int* __restrict__ row_ptr,
                                                    int* __restrict__ cursor, int n) {
    __shared__ int sdata[1024];
    __shared__ int s_run;
    const int t = threadIdx.x;
    if (t == 0) s_run = 0;
    __syncthreads();
    for (int base = 0; base < n; base += 1024) {
        int i = base + t;
        int v = (i < n) ? cnt[i] : 0;
        sdata[t] = v;
        __syncthreads();
        // Hillis-Steele inclusive scan
        for (int off = 1; off < 1024; off <<= 1) {
            int x = (t >= off) ? sdata[t - off] : 0;
            __syncthreads();
            sdata[t] += x;
            __syncthreads();
        }
        int run = s_run;
        __syncthreads();  // everyone read s_run before it is overwritten
        int incl = run + sdata[t];
        if (i < n) {
            row_ptr[i + 1] = incl;
            cursor[i] = incl - v;  // exclusive
        }
        if (t == 1023) s_run = incl;
        __syncthreads();
    }
    if (t == 0) row_ptr[0] = 0;
}

__global__ void fill_kernel(const int* __restrict__ dst, int* __restrict__ cursor,
                            int* __restrict__ eids, int E) {
    int e = blockIdx.x * blockDim.x + threadIdx.x;
    if (e < E) {
        int pos = atomicAdd(&cursor[dst[e]], 1);
        eids[pos] = e;
    }
}

// ---------------------------------------------------------------------------
// fp32 tiled GEMM: C[M,N] = A[M,K] @ B[K,N].  Requires N%BN==0, K%BK==0.
// 256 threads, thread tile TM x TN.
// ---------------------------------------------------------------------------
template <int BM, int BN, int BK, int TM, int TN>
__global__ __launch_bounds__(256) void gemm_f32(const float* __restrict__ A,
                                                const float* __restrict__ B,
                                                float* __restrict__ C,
                                                int M, int N, int K) {
    __shared__ float As[BK][BM + 4];  // stored transposed: As[k][m]
    __shared__ float Bs[BK][BN + 4];
    const int t = threadIdx.x;
    const int tx = t % (BN / TN);
    const int ty = t / (BN / TN);
    const int row0 = blockIdx.y * BM;
    const int col0 = blockIdx.x * BN;

    float acc[TM][TN] = {};

    for (int k0 = 0; k0 < K; k0 += BK) {
        // stage A tile (BM x BK), one float4 per element-group
#pragma unroll
        for (int i = 0; i < (BM * BK) / (4 * 256); ++i) {
            int idx = t + i * 256;
            int r = idx / (BK / 4);
            int c4 = (idx % (BK / 4)) * 4;
            int gr = row0 + r;
            if (gr >= M) gr = M - 1;  // clamp: duplicate row, stores are guarded
            float4 v = *(const float4*)&A[(size_t)gr * K + k0 + c4];
            As[c4 + 0][r] = v.x;
            As[c4 + 1][r] = v.y;
            As[c4 + 2][r] = v.z;
            As[c4 + 3][r] = v.w;
        }
        // stage B tile (BK x BN)
#pragma unroll
        for (int i = 0; i < (BK * BN) / (4 * 256); ++i) {
            int idx = t + i * 256;
            int r = idx / (BN / 4);
            int c4 = (idx % (BN / 4)) * 4;
            float4 v = *(const float4*)&B[(size_t)(k0 + r) * N + col0 + c4];
            *(float4*)&Bs[r][c4] = v;
        }
        __syncthreads();
#pragma unroll
        for (int kk = 0; kk < BK; ++kk) {
            float a[TM], b[TN];
#pragma unroll
            for (int i = 0; i < TM; i += 4)
                *(float4*)&a[i] = *(const float4*)&As[kk][ty * TM + i];
#pragma unroll
            for (int j = 0; j < TN; j += 4)
                *(float4*)&b[j] = *(const float4*)&Bs[kk][tx * TN + j];
#pragma unroll
            for (int i = 0; i < TM; ++i)
#pragma unroll
                for (int j = 0; j < TN; ++j) acc[i][j] += a[i] * b[j];
        }
        __syncthreads();
    }

#pragma unroll
    for (int i = 0; i < TM; ++i) {
        int r = row0 + ty * TM + i;
        if (r < M) {
#pragma unroll
            for (int j = 0; j < TN; j += 4)
                *(float4*)&C[(size_t)r * N + col0 + tx * TN + j] = *(const float4*)&acc[i][j];
        }
    }
}

// el[n,h] = sum_d feat[n,h,d]*al[h,d];  er likewise. One thread per (n,h).
template <int H, int D>
__global__ void eler_kernel(const float* __restrict__ feat, const float* __restrict__ al,
                            const float* __restrict__ ar, float* __restrict__ el,
                            float* __restrict__ er, int N) {
    int t = blockIdx.x * blockDim.x + threadIdx.x;
    if (t >= N * H) return;
    int n = t / H, h = t % H;
    const float* f = feat + (size_t)n * H * D + h * D;
    float sl = 0.f, sr = 0.f;
#pragma unroll
    for (int d = 0; d < D; d += 4) {
        float4 v = *(const float4*)&f[d];
        float4 a = *(const float4*)&al[h * D + d];
        float4 b = *(const float4*)&ar[h * D + d];
        sl += v.x * a.x + v.y * a.y + v.z * a.z + v.w * a.w;
        sr += v.x * b.x + v.y * b.y + v.z * b.z + v.w * b.w;
    }
    el[t] = sl;
    er[t] = sr;
}

__device__ __forceinline__ float leaky02(float x) { return x > 0.f ? x : 0.2f * x; }

// ---------------------------------------------------------------------------
// Edge-softmax aggregation, one 64-lane wave per dst node (4 waves / block).
// MODE 0: out[n, H*D] = ELU(sum_e alpha*feat[src])        (layer 1)
// MODE 1: out[n, D]   = mean_h(sum_e alpha*feat[src])     (layer 2, final)
// ---------------------------------------------------------------------------
template <int H, int D, int MODE>
__global__ __launch_bounds__(256) void gat_aggregate(
    const float* __restrict__ feat, const float* __restrict__ el,
    const float* __restrict__ er, const int* __restrict__ row_ptr,
    const int* __restrict__ eids, const int* __restrict__ src,
    float* __restrict__ out, int N) {
    constexpr int HD = H * D;
    constexpr int R = HD / 64;  // 4 (D=32) or 5 (D=40); HD is a multiple of 64 here
    __shared__ float red[4][HD];

    const int wid = threadIdx.x >> 6;
    const int lane = threadIdx.x & 63;
    const int n = blockIdx.x * 4 + wid;
    if (n >= N) return;

    const int beg = row_ptr[n];
    const int end = row_ptr[n + 1];

    // ---- phase A: per-head running max, then sum(exp) ----
    const int h8 = lane & 7;            // head handled by this lane in phase A
    const float er_nh = er[n * H + h8];
    float m_l = -INFINITY;
    for (int idx = beg + (lane >> 3); idx < end; idx += 8) {
        int e = eids[idx];
        int s = src[e];
        m_l = fmaxf(m_l, leaky02(el[s * H + h8] + er_nh));
    }
    m_l = fmaxf(m_l, __shfl_xor(m_l, 8));
    m_l = fmaxf(m_l, __shfl_xor(m_l, 16));
    m_l = fmaxf(m_l, __shfl_xor(m_l, 32));
    float s_l = 0.f;
    for (int idx = beg + (lane >> 3); idx < end; idx += 8) {
        int e = eids[idx];
        int s = src[e];
        s_l += __expf(leaky02(el[s * H + h8] + er_nh) - m_l);
    }
    s_l += __shfl_xor(s_l, 8);
    s_l += __shfl_xor(s_l, 16);
    s_l += __shfl_xor(s_l, 32);

    // broadcast per-head (m, 1/(s+eps), er) for this lane's phase-B slots
    float m_r[R], si_r[R], er_r[R];
    int h_r[R];
#pragma unroll
    for (int r = 0; r < R; ++r) {
        int i = lane + 64 * r;
        int h = i / D;
        h_r[r] = h;
        m_r[r] = __shfl(m_l, h);
        float s_h = __shfl(s_l, h);
        si_r[r] = 1.0f / (s_h + 1e-9f);
        er_r[r] = er[n * H + h];
    }

    // ---- phase B: accumulate alpha * feat[src] ----
    float acc[R] = {};
    for (int idx = beg; idx < end; ++idx) {
        int e = eids[idx];
        int s = src[e];
        const float* frow = feat + (size_t)s * HD;
#pragma unroll
        for (int r = 0; r < R; ++r) {
            int i = lane + 64 * r;
            float v = leaky02(el[s * H + h_r[r]] + er_r[r]);
            float w = __expf(v - m_r[r]) * si_r[r];
            acc[r] += w * frow[i];
        }
    }

    if (MODE == 0) {
#pragma unroll
        for (int r = 0; r < R; ++r) {
            float x = acc[r];
            x = x > 0.f ? x : expm1f(x);  // ELU
            out[(size_t)n * HD + lane + 64 * r] = x;
        }
    } else {
        // head mean: out[n, d] = (1/H) * sum_h acc[h*D+d]
#pragma unroll
        for (int r = 0; r < R; ++r) red[wid][lane + 64 * r] = acc[r];
        // same-wave LDS RAW; compiler orders ds_write->ds_read with lgkmcnt
        if (lane < D) {
            float s = 0.f;
#pragma unroll
            for (int hh = 0; hh < H; ++hh) s += red[wid][hh * D + lane];
            out[(size_t)n * D + lane] = s * (1.0f / H);
        }
    }
}

// ---------------------------------------------------------------------------

extern "C" void kernel_launch(void* const* d_in, const int* in_sizes, int n_in,
                              void* d_out, int out_size, void* d_ws, size_t ws_size,
                              hipStream_t stream) {
    const float* features = (const float*)d_in[0];
    const int* src = (const int*)d_in[1];
    const int* dst = (const int*)d_in[2];
    const float* W1 = (const float*)d_in[3];
    const float* al1 = (const float*)d_in[4];
    const float* ar1 = (const float*)d_in[5];
    const float* W2 = (const float*)d_in[6];
    const float* al2 = (const float*)d_in[7];
    const float* ar2 = (const float*)d_in[8];

    const int N = in_sizes[0] / 512;  // 50000
    const int E = in_sizes[1];        // 800000

    char* ws = (char*)d_ws;
    size_t off = 0;
    auto alloc = [&](size_t bytes) -> void* {
        void* p = ws + off;
        off = (off + bytes + 255) & ~(size_t)255;
        return p;
    };
    float* feat1 = (float*)alloc((size_t)N * 256 * 4);
    float* hbuf  = (float*)alloc((size_t)N * 256 * 4);
    float* feat2 = (float*)alloc((size_t)N * 320 * 4);
    float* el1 = (float*)alloc((size_t)N * 8 * 4);
    float* er1 = (float*)alloc((size_t)N * 8 * 4);
    float* el2 = (float*)alloc((size_t)N * 8 * 4);
    float* er2 = (float*)alloc((size_t)N * 8 * 4);
    int* cnt = (int*)alloc((size_t)N * 4);
    int* row_ptr = (int*)alloc((size_t)(N + 1) * 4);
    int* cursor = (int*)alloc((size_t)N * 4);
    int* eids = (int*)alloc((size_t)E * 4);

    // ---- CSR build (dst-sorted edge lists) ----
    hipMemsetAsync(cnt, 0, (size_t)N * 4, stream);
    hist_kernel<<<(E + 255) / 256, 256, 0, stream>>>(dst, cnt, E);
    scan_kernel<<<1, 1024, 0, stream>>>(cnt, row_ptr, cursor, N);
    fill_kernel<<<(E + 255) / 256, 256, 0, stream>>>(dst, cursor, eids, E);

    // ---- layer 1 ----
    gemm_f32<128, 128, 16, 8, 8>
        <<<dim3(256 / 128, (N + 127) / 128), 256, 0, stream>>>(features, W1, feat1, N, 256, 512);
    eler_kernel<8, 32><<<(N * 8 + 255) / 256, 256, 0, stream>>>(feat1, al1, ar1, el1, er1, N);
    gat_aggregate<8, 32, 0>
        <<<(N + 3) / 4, 256, 0, stream>>>(feat1, el1, er1, row_ptr, eids, src, hbuf, N);

    // ---- layer 2 ----
    gemm_f32<128, 64, 16, 8, 4>
        <<<dim3(320 / 64, (N + 127) / 128), 256, 0, stream>>>(hbuf, W2, feat2, N, 320, 256);
    eler_kernel<8, 40><<<(N * 8 + 255) / 256, 256, 0, stream>>>(feat2, al2, ar2, el2, er2, N);
    gat_aggregate<8, 40, 1>
        <<<(N + 3) / 4, 256, 0, stream>>>(feat2, el2, er2, row_ptr, eids, src, (float*)d_out, N);
}

// Round 2
// 726.770 us; speedup vs baseline: 1.2581x; 1.2581x over previous
//
#include <hip/hip_runtime.h>
#include <math.h>

typedef float f32x4 __attribute__((ext_vector_type(4)));
typedef __bf16 bf16x4 __attribute__((ext_vector_type(4)));
typedef __bf16 bf16x8 __attribute__((ext_vector_type(8)));

// ---------------------------------------------------------------------------
// GAT 2-layer forward.
// GEMMs: split-bf16 MFMA (hi/lo decomposition, 3 MFMA terms => ~fp32 accuracy).
// Aggregation: CSR by dst + one wave per dst node (unchanged from R1).
// ---------------------------------------------------------------------------

__global__ void hist_kernel(const int* __restrict__ dst, int* __restrict__ cnt, int E) {
    int e = blockIdx.x * blockDim.x + threadIdx.x;
    if (e < E) atomicAdd(&cnt[dst[e]], 1);
}

__global__ __launch_bounds__(1024) void scan_kernel(const int* __restrict__ cnt,
                                                    int* __restrict__ row_ptr,
                                                    int* __restrict__ cursor, int n) {
    __shared__ int sdata[1024];
    __shared__ int s_run;
    const int t = threadIdx.x;
    if (t == 0) s_run = 0;
    __syncthreads();
    for (int base = 0; base < n; base += 1024) {
        int i = base + t;
        int v = (i < n) ? cnt[i] : 0;
        sdata[t] = v;
        __syncthreads();
        for (int off = 1; off < 1024; off <<= 1) {
            int x = (t >= off) ? sdata[t - off] : 0;
            __syncthreads();
            sdata[t] += x;
            __syncthreads();
        }
        int run = s_run;
        __syncthreads();
        int incl = run + sdata[t];
        if (i < n) {
            row_ptr[i + 1] = incl;
            cursor[i] = incl - v;
        }
        if (t == 1023) s_run = incl;
        __syncthreads();
    }
    if (t == 0) row_ptr[0] = 0;
}

__global__ void fill_kernel(const int* __restrict__ dst, int* __restrict__ cursor,
                            int* __restrict__ eids, int E) {
    int e = blockIdx.x * blockDim.x + threadIdx.x;
    if (e < E) {
        int pos = atomicAdd(&cursor[dst[e]], 1);
        eids[pos] = e;
    }
}

// W[K][N] fp32 -> Wt_hi/Wt_lo[N][K] bf16 (transposed, split)
__global__ void split_w_kernel(const float* __restrict__ W, __bf16* __restrict__ Wth,
                               __bf16* __restrict__ Wtl, int K, int N) {
    int idx = blockIdx.x * blockDim.x + threadIdx.x;
    if (idx >= K * N) return;
    int k = idx / N, n = idx % N;
    float x = W[idx];
    __bf16 h = (__bf16)x;
    __bf16 l = (__bf16)(x - (float)h);
    Wth[(size_t)n * K + k] = h;
    Wtl[(size_t)n * K + k] = l;
}

// ---------------------------------------------------------------------------
// Split-bf16 MFMA GEMM: C[M,BN] = A[M,K] @ B[K,BN], B pre-split+transposed.
// Block: 256 threads = 4 waves, each wave owns 64 x (BN/4) of the 64 x BN tile.
// BK=32 = one mfma_f32_16x16x32_bf16 K-step. A converted fp32->hi/lo in-flight.
// LDS rows are 64B (32 bf16, no pad): frag reads (row=lane&15, kg=lane>>4) hit
// 8 distinct 16B spans x 8 addrs = the 1KB/128B floor (conflict-free).
// ---------------------------------------------------------------------------
template <int BN, int NREP>
__global__ __launch_bounds__(256, 2) void gemm_split_bf16(
    const float* __restrict__ A, const __bf16* __restrict__ Bth,
    const __bf16* __restrict__ Btl, float* __restrict__ C, int M, int K) {
    constexpr int WN = NREP * 16;  // per-wave column width; BN == 4*WN
    __shared__ __align__(16) __bf16 Ah[64][32], Al[64][32];
    __shared__ __align__(16) __bf16 Bh[BN][32], Bl[BN][32];

    const int t = threadIdx.x;
    const int lane = t & 63;
    const int wid = t >> 6;
    const int row0 = blockIdx.x * 64;
    const int colw = wid * WN;
    const int fr = lane & 15;
    const int kg = (lane >> 4) * 8;

    f32x4 acc[4][NREP] = {};

    for (int k0 = 0; k0 < K; k0 += 32) {
        // ---- stage A tile 64x32 fp32 -> hi/lo bf16 (2 float4 per thread) ----
#pragma unroll
        for (int p = 0; p < 2; ++p) {
            int idx = t + p * 256;
            int r = idx >> 3;
            int c4 = (idx & 7) * 4;
            int gr = row0 + r;
            if (gr >= M) gr = M - 1;  // clamp; stores are guarded
            float4 v = *(const float4*)&A[(size_t)gr * K + k0 + c4];
            __bf16 h0 = (__bf16)v.x, h1 = (__bf16)v.y, h2 = (__bf16)v.z, h3 = (__bf16)v.w;
            bf16x4 hv = {h0, h1, h2, h3};
            bf16x4 lv = {(__bf16)(v.x - (float)h0), (__bf16)(v.y - (float)h1),
                         (__bf16)(v.z - (float)h2), (__bf16)(v.w - (float)h3)};
            *(bf16x4*)&Ah[r][c4] = hv;
            *(bf16x4*)&Al[r][c4] = lv;
        }
        // ---- stage B tile BNx32 bf16 hi+lo (16B chunks) ----
#pragma unroll
        for (int p = 0; p < BN / 64; ++p) {
            int idx = t + p * 256;
            int n = idx >> 2;
            int c = (idx & 3) * 8;
            *(bf16x8*)&Bh[n][c] = *(const bf16x8*)&Bth[(size_t)n * K + k0 + c];
            *(bf16x8*)&Bl[n][c] = *(const bf16x8*)&Btl[(size_t)n * K + k0 + c];
        }
        __syncthreads();

        bf16x8 ah[4], al[4], bh[NREP], bl[NREP];
#pragma unroll
        for (int m = 0; m < 4; ++m) {
            ah[m] = *(const bf16x8*)&Ah[fr + m * 16][kg];
            al[m] = *(const bf16x8*)&Al[fr + m * 16][kg];
        }
#pragma unroll
        for (int n = 0; n < NREP; ++n) {
            bh[n] = *(const bf16x8*)&Bh[colw + n * 16 + fr][kg];
            bl[n] = *(const bf16x8*)&Bl[colw + n * 16 + fr][kg];
        }
#pragma unroll
        for (int m = 0; m < 4; ++m)
#pragma unroll
            for (int n = 0; n < NREP; ++n) {
                acc[m][n] = __builtin_amdgcn_mfma_f32_16x16x32_bf16(ah[m], bh[n], acc[m][n], 0, 0, 0);
                acc[m][n] = __builtin_amdgcn_mfma_f32_16x16x32_bf16(al[m], bh[n], acc[m][n], 0, 0, 0);
                acc[m][n] = __builtin_amdgcn_mfma_f32_16x16x32_bf16(ah[m], bl[n], acc[m][n], 0, 0, 0);
            }
        __syncthreads();
    }

    // ---- epilogue: C/D layout col=lane&15, row=(lane>>4)*4+reg ----
#pragma unroll
    for (int m = 0; m < 4; ++m) {
        int rbase = row0 + m * 16 + (lane >> 4) * 4;
#pragma unroll
        for (int n = 0; n < NREP; ++n) {
            int col = colw + n * 16 + fr;
#pragma unroll
            for (int i = 0; i < 4; ++i) {
                int r = rbase + i;
                if (r < M) C[(size_t)r * BN + col] = acc[m][n][i];
            }
        }
    }
}

// el[n,h] = sum_d feat[n,h,d]*al[h,d];  er likewise. One thread per (n,h).
template <int H, int D>
__global__ void eler_kernel(const float* __restrict__ feat, const float* __restrict__ al,
                            const float* __restrict__ ar, float* __restrict__ el,
                            float* __restrict__ er, int N) {
    int t = blockIdx.x * blockDim.x + threadIdx.x;
    if (t >= N * H) return;
    int n = t / H, h = t % H;
    const float* f = feat + (size_t)n * H * D + h * D;
    float sl = 0.f, sr = 0.f;
#pragma unroll
    for (int d = 0; d < D; d += 4) {
        float4 v = *(const float4*)&f[d];
        float4 a = *(const float4*)&al[h * D + d];
        float4 b = *(const float4*)&ar[h * D + d];
        sl += v.x * a.x + v.y * a.y + v.z * a.z + v.w * a.w;
        sr += v.x * b.x + v.y * b.y + v.z * b.z + v.w * b.w;
    }
    el[t] = sl;
    er[t] = sr;
}

__device__ __forceinline__ float leaky02(float x) { return x > 0.f ? x : 0.2f * x; }

// ---------------------------------------------------------------------------
// Edge-softmax aggregation, one 64-lane wave per dst node (4 waves / block).
// MODE 0: out[n, H*D] = ELU(sum_e alpha*feat[src])        (layer 1)
// MODE 1: out[n, D]   = mean_h(sum_e alpha*feat[src])     (layer 2, final)
// ---------------------------------------------------------------------------
template <int H, int D, int MODE>
__global__ __launch_bounds__(256) void gat_aggregate(
    const float* __restrict__ feat, const float* __restrict__ el,
    const float* __restrict__ er, const int* __restrict__ row_ptr,
    const int* __restrict__ eids, const int* __restrict__ src,
    float* __restrict__ out, int N) {
    constexpr int HD = H * D;
    constexpr int R = HD / 64;
    __shared__ float red[4][HD];

    const int wid = threadIdx.x >> 6;
    const int lane = threadIdx.x & 63;
    const int n = blockIdx.x * 4 + wid;
    if (n >= N) return;

    const int beg = row_ptr[n];
    const int end = row_ptr[n + 1];

    // ---- phase A: per-head running max, then sum(exp) ----
    const int h8 = lane & 7;
    const float er_nh = er[n * H + h8];
    float m_l = -INFINITY;
    for (int idx = beg + (lane >> 3); idx < end; idx += 8) {
        int e = eids[idx];
        int s = src[e];
        m_l = fmaxf(m_l, leaky02(el[s * H + h8] + er_nh));
    }
    m_l = fmaxf(m_l, __shfl_xor(m_l, 8));
    m_l = fmaxf(m_l, __shfl_xor(m_l, 16));
    m_l = fmaxf(m_l, __shfl_xor(m_l, 32));
    float s_l = 0.f;
    for (int idx = beg + (lane >> 3); idx < end; idx += 8) {
        int e = eids[idx];
        int s = src[e];
        s_l += __expf(leaky02(el[s * H + h8] + er_nh) - m_l);
    }
    s_l += __shfl_xor(s_l, 8);
    s_l += __shfl_xor(s_l, 16);
    s_l += __shfl_xor(s_l, 32);

    float m_r[R], si_r[R], er_r[R];
    int h_r[R];
#pragma unroll
    for (int r = 0; r < R; ++r) {
        int i = lane + 64 * r;
        int h = i / D;
        h_r[r] = h;
        m_r[r] = __shfl(m_l, h);
        float s_h = __shfl(s_l, h);
        si_r[r] = 1.0f / (s_h + 1e-9f);
        er_r[r] = er[n * H + h];
    }

    // ---- phase B: accumulate alpha * feat[src] ----
    float acc[R] = {};
    for (int idx = beg; idx < end; ++idx) {
        int e = eids[idx];
        int s = src[e];
        const float* frow = feat + (size_t)s * HD;
#pragma unroll
        for (int r = 0; r < R; ++r) {
            int i = lane + 64 * r;
            float v = leaky02(el[s * H + h_r[r]] + er_r[r]);
            float w = __expf(v - m_r[r]) * si_r[r];
            acc[r] += w * frow[i];
        }
    }

    if (MODE == 0) {
#pragma unroll
        for (int r = 0; r < R; ++r) {
            float x = acc[r];
            x = x > 0.f ? x : expm1f(x);  // ELU
            out[(size_t)n * HD + lane + 64 * r] = x;
        }
    } else {
#pragma unroll
        for (int r = 0; r < R; ++r) red[wid][lane + 64 * r] = acc[r];
        if (lane < D) {
            float s = 0.f;
#pragma unroll
            for (int hh = 0; hh < H; ++hh) s += red[wid][hh * D + lane];
            out[(size_t)n * D + lane] = s * (1.0f / H);
        }
    }
}

// ---------------------------------------------------------------------------

extern "C" void kernel_launch(void* const* d_in, const int* in_sizes, int n_in,
                              void* d_out, int out_size, void* d_ws, size_t ws_size,
                              hipStream_t stream) {
    const float* features = (const float*)d_in[0];
    const int* src = (const int*)d_in[1];
    const int* dst = (const int*)d_in[2];
    const float* W1 = (const float*)d_in[3];
    const float* al1 = (const float*)d_in[4];
    const float* ar1 = (const float*)d_in[5];
    const float* W2 = (const float*)d_in[6];
    const float* al2 = (const float*)d_in[7];
    const float* ar2 = (const float*)d_in[8];

    const int N = in_sizes[0] / 512;  // 50000
    const int E = in_sizes[1];        // 800000

    char* ws = (char*)d_ws;
    size_t off = 0;
    auto alloc = [&](size_t bytes) -> void* {
        void* p = ws + off;
        off = (off + bytes + 255) & ~(size_t)255;
        return p;
    };
    float* feat1 = (float*)alloc((size_t)N * 256 * 4);
    float* hbuf = (float*)alloc((size_t)N * 256 * 4);
    float* feat2 = (float*)alloc((size_t)N * 320 * 4);
    float* el1 = (float*)alloc((size_t)N * 8 * 4);
    float* er1 = (float*)alloc((size_t)N * 8 * 4);
    float* el2 = (float*)alloc((size_t)N * 8 * 4);
    float* er2 = (float*)alloc((size_t)N * 8 * 4);
    int* cnt = (int*)alloc((size_t)N * 4);
    int* row_ptr = (int*)alloc((size_t)(N + 1) * 4);
    int* cursor = (int*)alloc((size_t)N * 4);
    int* eids = (int*)alloc((size_t)E * 4);
    __bf16* Wt1h = (__bf16*)alloc((size_t)512 * 256 * 2);
    __bf16* Wt1l = (__bf16*)alloc((size_t)512 * 256 * 2);
    __bf16* Wt2h = (__bf16*)alloc((size_t)256 * 320 * 2);
    __bf16* Wt2l = (__bf16*)alloc((size_t)256 * 320 * 2);

    // ---- CSR build (dst-sorted edge lists) ----
    hipMemsetAsync(cnt, 0, (size_t)N * 4, stream);
    hist_kernel<<<(E + 255) / 256, 256, 0, stream>>>(dst, cnt, E);
    scan_kernel<<<1, 1024, 0, stream>>>(cnt, row_ptr, cursor, N);
    fill_kernel<<<(E + 255) / 256, 256, 0, stream>>>(dst, cursor, eids, E);

    // ---- weight split/transpose ----
    split_w_kernel<<<(512 * 256 + 255) / 256, 256, 0, stream>>>(W1, Wt1h, Wt1l, 512, 256);
    split_w_kernel<<<(256 * 320 + 255) / 256, 256, 0, stream>>>(W2, Wt2h, Wt2l, 256, 320);

    const int mblk = (N + 63) / 64;

    // ---- layer 1 ----
    gemm_split_bf16<256, 4><<<mblk, 256, 0, stream>>>(features, Wt1h, Wt1l, feat1, N, 512);
    eler_kernel<8, 32><<<(N * 8 + 255) / 256, 256, 0, stream>>>(feat1, al1, ar1, el1, er1, N);
    gat_aggregate<8, 32, 0>
        <<<(N + 3) / 4, 256, 0, stream>>>(feat1, el1, er1, row_ptr, eids, src, hbuf, N);

    // ---- layer 2 ----
    gemm_split_bf16<320, 5><<<mblk, 256, 0, stream>>>(hbuf, Wt2h, Wt2l, feat2, N, 256);
    eler_kernel<8, 40><<<(N * 8 + 255) / 256, 256, 0, stream>>>(feat2, al2, ar2, el2, er2, N);
    gat_aggregate<8, 40, 1>
        <<<(N + 3) / 4, 256, 0, stream>>>(feat2, el2, er2, row_ptr, eids, src, (float*)d_out, N);
}

// Round 3
// 506.357 us; speedup vs baseline: 1.8058x; 1.4353x over previous
//
#include <hip/hip_runtime.h>
#include <math.h>

typedef float f32x4 __attribute__((ext_vector_type(4)));
typedef __bf16 bf16x2 __attribute__((ext_vector_type(2)));
typedef __bf16 bf16x4 __attribute__((ext_vector_type(4)));
typedef __bf16 bf16x8 __attribute__((ext_vector_type(8)));

// ---------------------------------------------------------------------------
// GAT 2-layer forward.
// GEMMs: split-bf16 MFMA (hi/lo, 3 terms => ~fp32 accuracy), writes fp32 + bf16.
// Aggregation: CSR by dst; edge-parallel score precompute (streaming pe[E][8]);
// node-wave softmax with 1 exp/edge + shfl broadcast; bf16 feat gather.
// ---------------------------------------------------------------------------

__global__ void hist_kernel(const int* __restrict__ dst, int* __restrict__ cnt, int E) {
    int e = blockIdx.x * blockDim.x + threadIdx.x;
    if (e < E) atomicAdd(&cnt[dst[e]], 1);
}

// blocked scan: per-block inclusive scan + block sums
__global__ __launch_bounds__(256) void scan_blk(const int* __restrict__ cnt,
                                                int* __restrict__ incl,
                                                int* __restrict__ bsum, int n) {
    __shared__ int sd[256];
    const int t = threadIdx.x;
    int i = blockIdx.x * 256 + t;
    int v = (i < n) ? cnt[i] : 0;
    sd[t] = v;
    __syncthreads();
#pragma unroll
    for (int off = 1; off < 256; off <<= 1) {
        int x = (t >= off) ? sd[t - off] : 0;
        __syncthreads();
        sd[t] += x;
        __syncthreads();
    }
    if (i < n) incl[i] = sd[t];
    if (t == 255) bsum[blockIdx.x] = sd[255];
}

// exclusive scan of block sums (single block; nb <= 256)
__global__ __launch_bounds__(256) void scan_top(const int* __restrict__ bsum,
                                                int* __restrict__ boff, int nb) {
    __shared__ int sd[256];
    const int t = threadIdx.x;
    int v = (t < nb) ? bsum[t] : 0;
    sd[t] = v;
    __syncthreads();
#pragma unroll
    for (int off = 1; off < 256; off <<= 1) {
        int x = (t >= off) ? sd[t - off] : 0;
        __syncthreads();
        sd[t] += x;
        __syncthreads();
    }
    if (t < nb) boff[t] = sd[t] - v;  // exclusive
}

__global__ void scan_fix(const int* __restrict__ incl, const int* __restrict__ boff,
                         const int* __restrict__ cnt, int* __restrict__ row_ptr,
                         int* __restrict__ cursor, int n) {
    int i = blockIdx.x * blockDim.x + threadIdx.x;
    if (i >= n) return;
    int total = incl[i] + boff[i >> 8];
    row_ptr[i + 1] = total;
    cursor[i] = total - cnt[i];
    if (i == 0) row_ptr[0] = 0;
}

// fill CSR-position-ordered src/dst arrays
__global__ void fill_kernel(const int* __restrict__ src, const int* __restrict__ dst,
                            int* __restrict__ cursor, int* __restrict__ ssrc,
                            int* __restrict__ sdst, int E) {
    int e = blockIdx.x * blockDim.x + threadIdx.x;
    if (e < E) {
        int d = dst[e];
        int pos = atomicAdd(&cursor[d], 1);
        ssrc[pos] = src[e];
        sdst[pos] = d;
    }
}

// W[K][N] fp32 -> Wt_hi/Wt_lo[N][K] bf16 (transposed, split)
__global__ void split_w_kernel(const float* __restrict__ W, __bf16* __restrict__ Wth,
                               __bf16* __restrict__ Wtl, int K, int N) {
    int idx = blockIdx.x * blockDim.x + threadIdx.x;
    if (idx >= K * N) return;
    int k = idx / N, n = idx % N;
    float x = W[idx];
    __bf16 h = (__bf16)x;
    __bf16 l = (__bf16)(x - (float)h);
    Wth[(size_t)n * K + k] = h;
    Wtl[(size_t)n * K + k] = l;
}

// ---------------------------------------------------------------------------
// Split-bf16 MFMA GEMM: C[M,BN] = A[M,K] @ B[K,BN]; writes fp32 C and bf16 Cb.
// ---------------------------------------------------------------------------
template <int BN, int NREP>
__global__ __launch_bounds__(256, 2) void gemm_split_bf16(
    const float* __restrict__ A, const __bf16* __restrict__ Bth,
    const __bf16* __restrict__ Btl, float* __restrict__ C, __bf16* __restrict__ Cb,
    int M, int K) {
    constexpr int WN = NREP * 16;
    __shared__ __align__(16) __bf16 Ah[64][32], Al[64][32];
    __shared__ __align__(16) __bf16 Bh[BN][32], Bl[BN][32];

    const int t = threadIdx.x;
    const int lane = t & 63;
    const int wid = t >> 6;
    const int row0 = blockIdx.x * 64;
    const int colw = wid * WN;
    const int fr = lane & 15;
    const int kg = (lane >> 4) * 8;

    f32x4 acc[4][NREP] = {};

    for (int k0 = 0; k0 < K; k0 += 32) {
#pragma unroll
        for (int p = 0; p < 2; ++p) {
            int idx = t + p * 256;
            int r = idx >> 3;
            int c4 = (idx & 7) * 4;
            int gr = row0 + r;
            if (gr >= M) gr = M - 1;
            float4 v = *(const float4*)&A[(size_t)gr * K + k0 + c4];
            __bf16 h0 = (__bf16)v.x, h1 = (__bf16)v.y, h2 = (__bf16)v.z, h3 = (__bf16)v.w;
            bf16x4 hv = {h0, h1, h2, h3};
            bf16x4 lv = {(__bf16)(v.x - (float)h0), (__bf16)(v.y - (float)h1),
                         (__bf16)(v.z - (float)h2), (__bf16)(v.w - (float)h3)};
            *(bf16x4*)&Ah[r][c4] = hv;
            *(bf16x4*)&Al[r][c4] = lv;
        }
#pragma unroll
        for (int p = 0; p < BN / 64; ++p) {
            int idx = t + p * 256;
            int n = idx >> 2;
            int c = (idx & 3) * 8;
            *(bf16x8*)&Bh[n][c] = *(const bf16x8*)&Bth[(size_t)n * K + k0 + c];
            *(bf16x8*)&Bl[n][c] = *(const bf16x8*)&Btl[(size_t)n * K + k0 + c];
        }
        __syncthreads();

        bf16x8 ah[4], al[4], bh[NREP], bl[NREP];
#pragma unroll
        for (int m = 0; m < 4; ++m) {
            ah[m] = *(const bf16x8*)&Ah[fr + m * 16][kg];
            al[m] = *(const bf16x8*)&Al[fr + m * 16][kg];
        }
#pragma unroll
        for (int n = 0; n < NREP; ++n) {
            bh[n] = *(const bf16x8*)&Bh[colw + n * 16 + fr][kg];
            bl[n] = *(const bf16x8*)&Bl[colw + n * 16 + fr][kg];
        }
#pragma unroll
        for (int m = 0; m < 4; ++m)
#pragma unroll
            for (int n = 0; n < NREP; ++n) {
                acc[m][n] = __builtin_amdgcn_mfma_f32_16x16x32_bf16(ah[m], bh[n], acc[m][n], 0, 0, 0);
                acc[m][n] = __builtin_amdgcn_mfma_f32_16x16x32_bf16(al[m], bh[n], acc[m][n], 0, 0, 0);
                acc[m][n] = __builtin_amdgcn_mfma_f32_16x16x32_bf16(ah[m], bl[n], acc[m][n], 0, 0, 0);
            }
        __syncthreads();
    }

#pragma unroll
    for (int m = 0; m < 4; ++m) {
        int rbase = row0 + m * 16 + (lane >> 4) * 4;
#pragma unroll
        for (int n = 0; n < NREP; ++n) {
            int col = colw + n * 16 + fr;
#pragma unroll
            for (int i = 0; i < 4; ++i) {
                int r = rbase + i;
                if (r < M) {
                    float v = acc[m][n][i];
                    C[(size_t)r * BN + col] = v;
                    Cb[(size_t)r * BN + col] = (__bf16)v;
                }
            }
        }
    }
}

// el[n,h] = sum_d feat[n,h,d]*al[h,d];  er likewise. One thread per (n,h).
template <int H, int D>
__global__ void eler_kernel(const float* __restrict__ feat, const float* __restrict__ al,
                            const float* __restrict__ ar, float* __restrict__ el,
                            float* __restrict__ er, int N) {
    int t = blockIdx.x * blockDim.x + threadIdx.x;
    if (t >= N * H) return;
    int n = t / H, h = t % H;
    const float* f = feat + (size_t)n * H * D + h * D;
    float sl = 0.f, sr = 0.f;
#pragma unroll
    for (int d = 0; d < D; d += 4) {
        float4 v = *(const float4*)&f[d];
        float4 a = *(const float4*)&al[h * D + d];
        float4 b = *(const float4*)&ar[h * D + d];
        sl += v.x * a.x + v.y * a.y + v.z * a.z + v.w * a.w;
        sr += v.x * b.x + v.y * b.y + v.z * b.z + v.w * b.w;
    }
    el[t] = sl;
    er[t] = sr;
}

__device__ __forceinline__ float leaky02(float x) { return x > 0.f ? x : 0.2f * x; }

// edge-parallel raw scores (CSR order): pe[pos][8] = leaky(el[s]+er[d])
__global__ void edge_score_kernel(const int* __restrict__ ssrc, const int* __restrict__ sdst,
                                  const float* __restrict__ el, const float* __restrict__ er,
                                  float* __restrict__ pe, int E) {
    int pos = blockIdx.x * blockDim.x + threadIdx.x;
    if (pos >= E) return;
    int s = ssrc[pos], d = sdst[pos];
    float4 l0 = *(const float4*)&el[(size_t)s * 8];
    float4 l1 = *(const float4*)&el[(size_t)s * 8 + 4];
    float4 r0 = *(const float4*)&er[(size_t)d * 8];
    float4 r1 = *(const float4*)&er[(size_t)d * 8 + 4];
    float4 o0 = {leaky02(l0.x + r0.x), leaky02(l0.y + r0.y),
                 leaky02(l0.z + r0.z), leaky02(l0.w + r0.w)};
    float4 o1 = {leaky02(l1.x + r1.x), leaky02(l1.y + r1.y),
                 leaky02(l1.z + r1.z), leaky02(l1.w + r1.w)};
    *(float4*)&pe[(size_t)pos * 8] = o0;
    *(float4*)&pe[(size_t)pos * 8 + 4] = o1;
}

// ---------------------------------------------------------------------------
// Edge-softmax aggregation, one wave per dst node. H=8.
// Phase A: stream pe coalesced (8 edges x 8 heads per wave-read), shfl reduce.
// Phase B: 1 exp per edge per lane (own head), shfl-broadcast alpha, bf16 gather.
// MODE 0 (D=32): out[n,256] = ELU(sum)   MODE 1 (D=40): out[n,40] = head-mean.
// ---------------------------------------------------------------------------
template <int D, int MODE>
__global__ __launch_bounds__(256) void gat_aggregate(
    const __bf16* __restrict__ featb, const float* __restrict__ pe,
    const int* __restrict__ row_ptr, const int* __restrict__ ssrc,
    float* __restrict__ out, int N) {
    constexpr int HD = 8 * D;          // 256 or 320
    constexpr int TAIL = HD - 256;     // 0 or 64
    __shared__ float red[4][MODE ? HD : 1];

    const int wid = threadIdx.x >> 6;
    const int lane = threadIdx.x & 63;
    const int n = blockIdx.x * 4 + wid;
    if (n >= N) return;

    const int beg = row_ptr[n];
    const int end = row_ptr[n + 1];
    const int hl = lane & 7;      // this lane's head for scores
    const int sl = lane >> 3;     // this lane's edge slot in phase A

    // ---- phase A: per-head max, then sum(exp) over coalesced pe stream ----
    float m_l = -INFINITY;
    for (int idx = beg + sl; idx < end; idx += 8)
        m_l = fmaxf(m_l, pe[(size_t)idx * 8 + hl]);
    m_l = fmaxf(m_l, __shfl_xor(m_l, 8));
    m_l = fmaxf(m_l, __shfl_xor(m_l, 16));
    m_l = fmaxf(m_l, __shfl_xor(m_l, 32));
    float s_l = 0.f;
    for (int idx = beg + sl; idx < end; idx += 8)
        s_l += __expf(pe[(size_t)idx * 8 + hl] - m_l);
    s_l += __shfl_xor(s_l, 8);
    s_l += __shfl_xor(s_l, 16);
    s_l += __shfl_xor(s_l, 32);
    const float si_l = 1.0f / (s_l + 1e-9f);

    // per-lane head assignment for gather slots
    int hg[2], ht = 0;
#pragma unroll
    for (int g = 0; g < 2; ++g) hg[g] = (128 * g + 2 * lane) / D;
    if (TAIL) ht = (256 + lane) / D;

    // ---- phase B: accumulate alpha * featb[src] ----
    float acc[2][2] = {};
    float acct = 0.f;
    for (int idx = beg; idx < end; ++idx) {
        int s = ssrc[idx];
        float a = __expf(pe[(size_t)idx * 8 + hl] - m_l) * si_l;
        const __bf16* frow = featb + (size_t)s * HD;
#pragma unroll
        for (int g = 0; g < 2; ++g) {
            float w = __shfl(a, hg[g]);
            bf16x2 p = *(const bf16x2*)&frow[128 * g + 2 * lane];
            acc[g][0] += w * (float)p.x;
            acc[g][1] += w * (float)p.y;
        }
        if (TAIL) {
            float w = __shfl(a, ht);
            acct += w * (float)frow[256 + lane];
        }
    }

    if (MODE == 0) {
#pragma unroll
        for (int g = 0; g < 2; ++g) {
            float x0 = acc[g][0], x1 = acc[g][1];
            x0 = x0 > 0.f ? x0 : expm1f(x0);
            x1 = x1 > 0.f ? x1 : expm1f(x1);
            float2 v = {x0, x1};
            *(float2*)&out[(size_t)n * 256 + 128 * g + 2 * lane] = v;
        }
    } else {
#pragma unroll
        for (int g = 0; g < 2; ++g) {
            red[wid][128 * g + 2 * lane] = acc[g][0];
            red[wid][128 * g + 2 * lane + 1] = acc[g][1];
        }
        red[wid][256 + lane] = acct;
        if (lane < D) {
            float s = 0.f;
#pragma unroll
            for (int hh = 0; hh < 8; ++hh) s += red[wid][hh * D + lane];
            out[(size_t)n * D + lane] = s * 0.125f;
        }
    }
}

// ---------------------------------------------------------------------------

extern "C" void kernel_launch(void* const* d_in, const int* in_sizes, int n_in,
                              void* d_out, int out_size, void* d_ws, size_t ws_size,
                              hipStream_t stream) {
    const float* features = (const float*)d_in[0];
    const int* src = (const int*)d_in[1];
    const int* dst = (const int*)d_in[2];
    const float* W1 = (const float*)d_in[3];
    const float* al1 = (const float*)d_in[4];
    const float* ar1 = (const float*)d_in[5];
    const float* W2 = (const float*)d_in[6];
    const float* al2 = (const float*)d_in[7];
    const float* ar2 = (const float*)d_in[8];

    const int N = in_sizes[0] / 512;  // 50000
    const int E = in_sizes[1];        // 800000

    char* ws = (char*)d_ws;
    size_t off = 0;
    auto alloc = [&](size_t bytes) -> void* {
        void* p = ws + off;
        off = (off + bytes + 255) & ~(size_t)255;
        return p;
    };
    float* feat1 = (float*)alloc((size_t)N * 256 * 4);   // aliased by pe after eler1
    __bf16* feat1b = (__bf16*)alloc((size_t)N * 256 * 2);
    float* hbuf = (float*)alloc((size_t)N * 256 * 4);
    float* feat2 = (float*)alloc((size_t)N * 320 * 4);
    __bf16* feat2b = (__bf16*)alloc((size_t)N * 320 * 2);
    float* el1 = (float*)alloc((size_t)N * 8 * 4);
    float* er1 = (float*)alloc((size_t)N * 8 * 4);
    float* el2 = (float*)alloc((size_t)N * 8 * 4);
    float* er2 = (float*)alloc((size_t)N * 8 * 4);
    int* cnt = (int*)alloc((size_t)N * 4);
    int* incl = (int*)alloc((size_t)N * 4);
    int* row_ptr = (int*)alloc((size_t)(N + 1) * 4);
    int* cursor = (int*)alloc((size_t)N * 4);
    int* bsum = (int*)alloc(256 * 4);
    int* boff = (int*)alloc(256 * 4);
    int* ssrc = (int*)alloc((size_t)E * 4);
    int* sdst = (int*)alloc((size_t)E * 4);
    __bf16* Wt1h = (__bf16*)alloc((size_t)512 * 256 * 2);
    __bf16* Wt1l = (__bf16*)alloc((size_t)512 * 256 * 2);
    __bf16* Wt2h = (__bf16*)alloc((size_t)256 * 320 * 2);
    __bf16* Wt2l = (__bf16*)alloc((size_t)256 * 320 * 2);
    float* pe = feat1;  // alias: feat1 (fp32) is dead after eler1

    const int NB = (N + 255) / 256;  // 196 <= 256

    // ---- CSR build ----
    hipMemsetAsync(cnt, 0, (size_t)N * 4, stream);
    hist_kernel<<<(E + 255) / 256, 256, 0, stream>>>(dst, cnt, E);
    scan_blk<<<NB, 256, 0, stream>>>(cnt, incl, bsum, N);
    scan_top<<<1, 256, 0, stream>>>(bsum, boff, NB);
    scan_fix<<<NB, 256, 0, stream>>>(incl, boff, cnt, row_ptr, cursor, N);
    fill_kernel<<<(E + 255) / 256, 256, 0, stream>>>(src, dst, cursor, ssrc, sdst, E);

    // ---- weight split/transpose ----
    split_w_kernel<<<(512 * 256 + 255) / 256, 256, 0, stream>>>(W1, Wt1h, Wt1l, 512, 256);
    split_w_kernel<<<(256 * 320 + 255) / 256, 256, 0, stream>>>(W2, Wt2h, Wt2l, 256, 320);

    const int mblk = (N + 63) / 64;

    // ---- layer 1 ----
    gemm_split_bf16<256, 4>
        <<<mblk, 256, 0, stream>>>(features, Wt1h, Wt1l, feat1, feat1b, N, 512);
    eler_kernel<8, 32><<<(N * 8 + 255) / 256, 256, 0, stream>>>(feat1, al1, ar1, el1, er1, N);
    edge_score_kernel<<<(E + 255) / 256, 256, 0, stream>>>(ssrc, sdst, el1, er1, pe, E);
    gat_aggregate<32, 0>
        <<<(N + 3) / 4, 256, 0, stream>>>(feat1b, pe, row_ptr, ssrc, hbuf, N);

    // ---- layer 2 ----
    gemm_split_bf16<320, 5>
        <<<mblk, 256, 0, stream>>>(hbuf, Wt2h, Wt2l, feat2, feat2b, N, 256);
    eler_kernel<8, 40><<<(N * 8 + 255) / 256, 256, 0, stream>>>(feat2, al2, ar2, el2, er2, N);
    edge_score_kernel<<<(E + 255) / 256, 256, 0, stream>>>(ssrc, sdst, el2, er2, pe, E);
    gat_aggregate<40, 1>
        <<<(N + 3) / 4, 256, 0, stream>>>(feat2b, pe, row_ptr, ssrc, (float*)d_out, N);
}

// Round 4
// 387.884 us; speedup vs baseline: 2.3573x; 1.3054x over previous
//
#include <hip/hip_runtime.h>
#include <math.h>

typedef float f32x4 __attribute__((ext_vector_type(4)));
typedef __bf16 bf16x2 __attribute__((ext_vector_type(2)));
typedef __bf16 bf16x4 __attribute__((ext_vector_type(4)));
typedef __bf16 bf16x8 __attribute__((ext_vector_type(8)));

// ---------------------------------------------------------------------------
// GAT 2-layer forward.
// GEMMs: split-bf16 MFMA (hi/lo, 3 terms => ~fp32 accuracy), fused el/er
// epilogue (fp32 acc -> LDS -> dot with al/ar), writes bf16 feat only.
// Aggregation: CSR by dst; streaming pe[E][8] scores; 4x-unrolled gather.
// ---------------------------------------------------------------------------

__global__ void hist_kernel(const int* __restrict__ dst, int* __restrict__ cnt, int E) {
    int e = blockIdx.x * blockDim.x + threadIdx.x;
    if (e < E) atomicAdd(&cnt[dst[e]], 1);
}

__global__ __launch_bounds__(256) void scan_blk(const int* __restrict__ cnt,
                                                int* __restrict__ incl,
                                                int* __restrict__ bsum, int n) {
    __shared__ int sd[256];
    const int t = threadIdx.x;
    int i = blockIdx.x * 256 + t;
    int v = (i < n) ? cnt[i] : 0;
    sd[t] = v;
    __syncthreads();
#pragma unroll
    for (int off = 1; off < 256; off <<= 1) {
        int x = (t >= off) ? sd[t - off] : 0;
        __syncthreads();
        sd[t] += x;
        __syncthreads();
    }
    if (i < n) incl[i] = sd[t];
    if (t == 255) bsum[blockIdx.x] = sd[255];
}

__global__ __launch_bounds__(256) void scan_top(const int* __restrict__ bsum,
                                                int* __restrict__ boff, int nb) {
    __shared__ int sd[256];
    const int t = threadIdx.x;
    int v = (t < nb) ? bsum[t] : 0;
    sd[t] = v;
    __syncthreads();
#pragma unroll
    for (int off = 1; off < 256; off <<= 1) {
        int x = (t >= off) ? sd[t - off] : 0;
        __syncthreads();
        sd[t] += x;
        __syncthreads();
    }
    if (t < nb) boff[t] = sd[t] - v;
}

__global__ void scan_fix(const int* __restrict__ incl, const int* __restrict__ boff,
                         const int* __restrict__ cnt, int* __restrict__ row_ptr,
                         int* __restrict__ cursor, int n) {
    int i = blockIdx.x * blockDim.x + threadIdx.x;
    if (i >= n) return;
    int total = incl[i] + boff[i >> 8];
    row_ptr[i + 1] = total;
    cursor[i] = total - cnt[i];
    if (i == 0) row_ptr[0] = 0;
}

__global__ void fill_kernel(const int* __restrict__ src, const int* __restrict__ dst,
                            int* __restrict__ cursor, int* __restrict__ ssrc,
                            int* __restrict__ sdst, int E) {
    int e = blockIdx.x * blockDim.x + threadIdx.x;
    if (e < E) {
        int d = dst[e];
        int pos = atomicAdd(&cursor[d], 1);
        ssrc[pos] = src[e];
        sdst[pos] = d;
    }
}

// W[K][N] fp32 -> Wt_hi/Wt_lo[N][K] bf16 (transposed, split)
__global__ void split_w_kernel(const float* __restrict__ W, __bf16* __restrict__ Wth,
                               __bf16* __restrict__ Wtl, int K, int N) {
    int idx = blockIdx.x * blockDim.x + threadIdx.x;
    if (idx >= K * N) return;
    int k = idx / N, n = idx % N;
    float x = W[idx];
    __bf16 h = (__bf16)x;
    __bf16 l = (__bf16)(x - (float)h);
    Wth[(size_t)n * K + k] = h;
    Wtl[(size_t)n * K + k] = l;
}

// ---------------------------------------------------------------------------
// Split-bf16 MFMA GEMM + fused el/er epilogue.
// feat[M,BN] = A[M,K] @ B[K,BN] (written bf16);
// el[r,h] = sum_d feat_f32[r][h*D+d]*al[h][d], er likewise (fp32 exact).
// Epilogue stages the fp32 acc tile in LDS in two half-tiles (LDS reused
// from staging via union).
// ---------------------------------------------------------------------------
template <int BN, int NREP>
__global__ __launch_bounds__(256, 2) void gemm_fused(
    const float* __restrict__ A, const __bf16* __restrict__ Bth,
    const __bf16* __restrict__ Btl, const float* __restrict__ al,
    const float* __restrict__ ar, __bf16* __restrict__ featb,
    float* __restrict__ el, float* __restrict__ er, int M, int K) {
    constexpr int WN = NREP * 16;
    constexpr int D = BN / 8;
    constexpr int HBN = BN / 2;

    struct Stage {
        __bf16 Ah[64][32];
        __bf16 Al[64][32];
        __bf16 Bh[BN][32];
        __bf16 Bl[BN][32];
    };
    union Smem {
        Stage s;
        float ctile[64][HBN + 4];
    };
    __shared__ __align__(16) Smem u;

    const int t = threadIdx.x;
    const int lane = t & 63;
    const int wid = t >> 6;
    const int row0 = blockIdx.x * 64;
    const int colw = wid * WN;
    const int fr = lane & 15;
    const int kg = (lane >> 4) * 8;

    f32x4 acc[4][NREP] = {};

    for (int k0 = 0; k0 < K; k0 += 32) {
#pragma unroll
        for (int p = 0; p < 2; ++p) {
            int idx = t + p * 256;
            int r = idx >> 3;
            int c4 = (idx & 7) * 4;
            int gr = row0 + r;
            if (gr >= M) gr = M - 1;
            float4 v = *(const float4*)&A[(size_t)gr * K + k0 + c4];
            __bf16 h0 = (__bf16)v.x, h1 = (__bf16)v.y, h2 = (__bf16)v.z, h3 = (__bf16)v.w;
            bf16x4 hv = {h0, h1, h2, h3};
            bf16x4 lv = {(__bf16)(v.x - (float)h0), (__bf16)(v.y - (float)h1),
                         (__bf16)(v.z - (float)h2), (__bf16)(v.w - (float)h3)};
            *(bf16x4*)&u.s.Ah[r][c4] = hv;
            *(bf16x4*)&u.s.Al[r][c4] = lv;
        }
#pragma unroll
        for (int p = 0; p < BN / 64; ++p) {
            int idx = t + p * 256;
            int n = idx >> 2;
            int c = (idx & 3) * 8;
            *(bf16x8*)&u.s.Bh[n][c] = *(const bf16x8*)&Bth[(size_t)n * K + k0 + c];
            *(bf16x8*)&u.s.Bl[n][c] = *(const bf16x8*)&Btl[(size_t)n * K + k0 + c];
        }
        __syncthreads();

        bf16x8 ah[4], alv[4], bh[NREP], bl[NREP];
#pragma unroll
        for (int m = 0; m < 4; ++m) {
            ah[m] = *(const bf16x8*)&u.s.Ah[fr + m * 16][kg];
            alv[m] = *(const bf16x8*)&u.s.Al[fr + m * 16][kg];
        }
#pragma unroll
        for (int n = 0; n < NREP; ++n) {
            bh[n] = *(const bf16x8*)&u.s.Bh[colw + n * 16 + fr][kg];
            bl[n] = *(const bf16x8*)&u.s.Bl[colw + n * 16 + fr][kg];
        }
#pragma unroll
        for (int m = 0; m < 4; ++m)
#pragma unroll
            for (int n = 0; n < NREP; ++n) {
                acc[m][n] = __builtin_amdgcn_mfma_f32_16x16x32_bf16(ah[m], bh[n], acc[m][n], 0, 0, 0);
                acc[m][n] = __builtin_amdgcn_mfma_f32_16x16x32_bf16(alv[m], bh[n], acc[m][n], 0, 0, 0);
                acc[m][n] = __builtin_amdgcn_mfma_f32_16x16x32_bf16(ah[m], bl[n], acc[m][n], 0, 0, 0);
            }
        __syncthreads();
    }

    // ---- epilogue part 1: direct bf16 feat stores ----
#pragma unroll
    for (int m = 0; m < 4; ++m) {
        int rbase = row0 + m * 16 + (lane >> 4) * 4;
#pragma unroll
        for (int n = 0; n < NREP; ++n) {
            int col = colw + n * 16 + fr;
#pragma unroll
            for (int i = 0; i < 4; ++i) {
                int r = rbase + i;
                if (r < M) featb[(size_t)r * BN + col] = (__bf16)acc[m][n][i];
            }
        }
    }

    // ---- epilogue part 2: el/er via LDS half-tiles ----
#pragma unroll
    for (int half = 0; half < 2; ++half) {
        __syncthreads();
        if ((wid >> 1) == half) {
            int cbase = colw - half * HBN;
#pragma unroll
            for (int m = 0; m < 4; ++m) {
                int rb = m * 16 + (lane >> 4) * 4;
#pragma unroll
                for (int n = 0; n < NREP; ++n) {
                    int lc = cbase + n * 16 + fr;
#pragma unroll
                    for (int i = 0; i < 4; ++i) u.ctile[rb + i][lc] = acc[m][n][i];
                }
            }
        }
        __syncthreads();
        // 256 threads: r = t&63, head = half*4 + (t>>6)
        int r = t & 63;
        int hh = t >> 6;
        int h = half * 4 + hh;
        float sl = 0.f, sr = 0.f;
#pragma unroll
        for (int d = 0; d < D; ++d) {
            float v = u.ctile[r][hh * D + d];
            sl += v * al[h * D + d];
            sr += v * ar[h * D + d];
        }
        int gr = row0 + r;
        if (gr < M) {
            el[(size_t)gr * 8 + h] = sl;
            er[(size_t)gr * 8 + h] = sr;
        }
    }
}

__device__ __forceinline__ float leaky02(float x) { return x > 0.f ? x : 0.2f * x; }

// edge-parallel raw scores (CSR order): pe[pos][8] = leaky(el[s]+er[d])
__global__ void edge_score_kernel(const int* __restrict__ ssrc, const int* __restrict__ sdst,
                                  const float* __restrict__ el, const float* __restrict__ er,
                                  float* __restrict__ pe, int E) {
    int pos = blockIdx.x * blockDim.x + threadIdx.x;
    if (pos >= E) return;
    int s = ssrc[pos], d = sdst[pos];
    float4 l0 = *(const float4*)&el[(size_t)s * 8];
    float4 l1 = *(const float4*)&el[(size_t)s * 8 + 4];
    float4 r0 = *(const float4*)&er[(size_t)d * 8];
    float4 r1 = *(const float4*)&er[(size_t)d * 8 + 4];
    float4 o0 = {leaky02(l0.x + r0.x), leaky02(l0.y + r0.y),
                 leaky02(l0.z + r0.z), leaky02(l0.w + r0.w)};
    float4 o1 = {leaky02(l1.x + r1.x), leaky02(l1.y + r1.y),
                 leaky02(l1.z + r1.z), leaky02(l1.w + r1.w)};
    *(float4*)&pe[(size_t)pos * 8] = o0;
    *(float4*)&pe[(size_t)pos * 8 + 4] = o1;
}

// ---------------------------------------------------------------------------
// Edge-softmax aggregation, one wave per dst node. H=8. Phase-B 4x unrolled
// (batched independent gathers -> 4x MLP per wave).
// MODE 0 (D=32): out[n,256] = ELU(sum)   MODE 1 (D=40): out[n,40] = head-mean.
// ---------------------------------------------------------------------------
template <int D, int MODE>
__global__ __launch_bounds__(256) void gat_aggregate(
    const __bf16* __restrict__ featb, const float* __restrict__ pe,
    const int* __restrict__ row_ptr, const int* __restrict__ ssrc,
    float* __restrict__ out, int N) {
    constexpr int HD = 8 * D;
    constexpr int TAIL = HD - 256;
    __shared__ float red[4][MODE ? HD : 1];

    const int wid = threadIdx.x >> 6;
    const int lane = threadIdx.x & 63;
    const int n = blockIdx.x * 4 + wid;
    if (n >= N) return;

    const int beg = row_ptr[n];
    const int end = row_ptr[n + 1];
    const int hl = lane & 7;
    const int sl = lane >> 3;

    // ---- phase A: per-head max, then sum(exp) ----
    float m_l = -INFINITY;
    for (int idx = beg + sl; idx < end; idx += 8)
        m_l = fmaxf(m_l, pe[(size_t)idx * 8 + hl]);
    m_l = fmaxf(m_l, __shfl_xor(m_l, 8));
    m_l = fmaxf(m_l, __shfl_xor(m_l, 16));
    m_l = fmaxf(m_l, __shfl_xor(m_l, 32));
    float s_l = 0.f;
    for (int idx = beg + sl; idx < end; idx += 8)
        s_l += __expf(pe[(size_t)idx * 8 + hl] - m_l);
    s_l += __shfl_xor(s_l, 8);
    s_l += __shfl_xor(s_l, 16);
    s_l += __shfl_xor(s_l, 32);
    const float si_l = 1.0f / (s_l + 1e-9f);

    int hg[2], ht = 0;
#pragma unroll
    for (int g = 0; g < 2; ++g) hg[g] = (128 * g + 2 * lane) / D;
    if (TAIL) ht = (256 + lane) / D;

    // ---- phase B: accumulate alpha * featb[src], 4x unrolled ----
    float acc[2][2] = {};
    float acct = 0.f;
    int idx = beg;
    for (; idx + 4 <= end; idx += 4) {
        int ss[4];
        float aa[4];
#pragma unroll
        for (int uu = 0; uu < 4; ++uu) ss[uu] = ssrc[idx + uu];
#pragma unroll
        for (int uu = 0; uu < 4; ++uu)
            aa[uu] = __expf(pe[(size_t)(idx + uu) * 8 + hl] - m_l) * si_l;
        bf16x2 p[4][2];
        __bf16 pt[4];
#pragma unroll
        for (int uu = 0; uu < 4; ++uu) {
            const __bf16* f = featb + (size_t)ss[uu] * HD;
            p[uu][0] = *(const bf16x2*)&f[2 * lane];
            p[uu][1] = *(const bf16x2*)&f[128 + 2 * lane];
            if (TAIL) pt[uu] = f[256 + lane];
        }
#pragma unroll
        for (int uu = 0; uu < 4; ++uu) {
            float w0 = __shfl(aa[uu], hg[0]);
            float w1 = __shfl(aa[uu], hg[1]);
            acc[0][0] += w0 * (float)p[uu][0].x;
            acc[0][1] += w0 * (float)p[uu][0].y;
            acc[1][0] += w1 * (float)p[uu][1].x;
            acc[1][1] += w1 * (float)p[uu][1].y;
            if (TAIL) {
                float wt = __shfl(aa[uu], ht);
                acct += wt * (float)pt[uu];
            }
        }
    }
    for (; idx < end; ++idx) {
        int s = ssrc[idx];
        float a = __expf(pe[(size_t)idx * 8 + hl] - m_l) * si_l;
        const __bf16* f = featb + (size_t)s * HD;
        float w0 = __shfl(a, hg[0]);
        float w1 = __shfl(a, hg[1]);
        bf16x2 p0 = *(const bf16x2*)&f[2 * lane];
        bf16x2 p1 = *(const bf16x2*)&f[128 + 2 * lane];
        acc[0][0] += w0 * (float)p0.x;
        acc[0][1] += w0 * (float)p0.y;
        acc[1][0] += w1 * (float)p1.x;
        acc[1][1] += w1 * (float)p1.y;
        if (TAIL) {
            float wt = __shfl(a, ht);
            acct += wt * (float)f[256 + lane];
        }
    }

    if (MODE == 0) {
#pragma unroll
        for (int g = 0; g < 2; ++g) {
            float x0 = acc[g][0], x1 = acc[g][1];
            x0 = x0 > 0.f ? x0 : expm1f(x0);
            x1 = x1 > 0.f ? x1 : expm1f(x1);
            float2 v = {x0, x1};
            *(float2*)&out[(size_t)n * 256 + 128 * g + 2 * lane] = v;
        }
    } else {
#pragma unroll
        for (int g = 0; g < 2; ++g) {
            red[wid][128 * g + 2 * lane] = acc[g][0];
            red[wid][128 * g + 2 * lane + 1] = acc[g][1];
        }
        red[wid][256 + lane] = acct;
        if (lane < D) {
            float s = 0.f;
#pragma unroll
            for (int hh = 0; hh < 8; ++hh) s += red[wid][hh * D + lane];
            out[(size_t)n * D + lane] = s * 0.125f;
        }
    }
}

// ---------------------------------------------------------------------------

extern "C" void kernel_launch(void* const* d_in, const int* in_sizes, int n_in,
                              void* d_out, int out_size, void* d_ws, size_t ws_size,
                              hipStream_t stream) {
    const float* features = (const float*)d_in[0];
    const int* src = (const int*)d_in[1];
    const int* dst = (const int*)d_in[2];
    const float* W1 = (const float*)d_in[3];
    const float* al1 = (const float*)d_in[4];
    const float* ar1 = (const float*)d_in[5];
    const float* W2 = (const float*)d_in[6];
    const float* al2 = (const float*)d_in[7];
    const float* ar2 = (const float*)d_in[8];

    const int N = in_sizes[0] / 512;  // 50000
    const int E = in_sizes[1];        // 800000

    char* ws = (char*)d_ws;
    size_t off = 0;
    auto alloc = [&](size_t bytes) -> void* {
        void* p = ws + off;
        off = (off + bytes + 255) & ~(size_t)255;
        return p;
    };
    __bf16* feat1b = (__bf16*)alloc((size_t)N * 256 * 2);
    float* hbuf = (float*)alloc((size_t)N * 256 * 4);
    __bf16* feat2b = (__bf16*)alloc((size_t)N * 320 * 2);
    float* pe = (float*)alloc((size_t)E * 8 * 4);
    float* el1 = (float*)alloc((size_t)N * 8 * 4);
    float* er1 = (float*)alloc((size_t)N * 8 * 4);
    float* el2 = (float*)alloc((size_t)N * 8 * 4);
    float* er2 = (float*)alloc((size_t)N * 8 * 4);
    int* cnt = (int*)alloc((size_t)N * 4);
    int* incl = (int*)alloc((size_t)N * 4);
    int* row_ptr = (int*)alloc((size_t)(N + 1) * 4);
    int* cursor = (int*)alloc((size_t)N * 4);
    int* bsum = (int*)alloc(256 * 4);
    int* boff = (int*)alloc(256 * 4);
    int* ssrc = (int*)alloc((size_t)E * 4);
    int* sdst = (int*)alloc((size_t)E * 4);
    __bf16* Wt1h = (__bf16*)alloc((size_t)512 * 256 * 2);
    __bf16* Wt1l = (__bf16*)alloc((size_t)512 * 256 * 2);
    __bf16* Wt2h = (__bf16*)alloc((size_t)256 * 320 * 2);
    __bf16* Wt2l = (__bf16*)alloc((size_t)256 * 320 * 2);

    const int NB = (N + 255) / 256;

    // ---- CSR build ----
    hipMemsetAsync(cnt, 0, (size_t)N * 4, stream);
    hist_kernel<<<(E + 255) / 256, 256, 0, stream>>>(dst, cnt, E);
    scan_blk<<<NB, 256, 0, stream>>>(cnt, incl, bsum, N);
    scan_top<<<1, 256, 0, stream>>>(bsum, boff, NB);
    scan_fix<<<NB, 256, 0, stream>>>(incl, boff, cnt, row_ptr, cursor, N);
    fill_kernel<<<(E + 255) / 256, 256, 0, stream>>>(src, dst, cursor, ssrc, sdst, E);

    // ---- weight split/transpose ----
    split_w_kernel<<<(512 * 256 + 255) / 256, 256, 0, stream>>>(W1, Wt1h, Wt1l, 512, 256);
    split_w_kernel<<<(256 * 320 + 255) / 256, 256, 0, stream>>>(W2, Wt2h, Wt2l, 256, 320);

    const int mblk = (N + 63) / 64;

    // ---- layer 1 ----
    gemm_fused<256, 4><<<mblk, 256, 0, stream>>>(features, Wt1h, Wt1l, al1, ar1,
                                                 feat1b, el1, er1, N, 512);
    edge_score_kernel<<<(E + 255) / 256, 256, 0, stream>>>(ssrc, sdst, el1, er1, pe, E);
    gat_aggregate<32, 0>
        <<<(N + 3) / 4, 256, 0, stream>>>(feat1b, pe, row_ptr, ssrc, hbuf, N);

    // ---- layer 2 ----
    gemm_fused<320, 5><<<mblk, 256, 0, stream>>>(hbuf, Wt2h, Wt2l, al2, ar2,
                                                 feat2b, el2, er2, N, 256);
    edge_score_kernel<<<(E + 255) / 256, 256, 0, stream>>>(ssrc, sdst, el2, er2, pe, E);
    gat_aggregate<40, 1>
        <<<(N + 3) / 4, 256, 0, stream>>>(feat2b, pe, row_ptr, ssrc, (float*)d_out, N);
}